// Round 2
// baseline (8806.622 us; speedup 1.0000x reference)
//
#include <hip/hip_runtime.h>
#include <math.h>

// Problem constants
#define SEQL 128
#define NB   32
#define EMBD 300
#define HH   400      // hidden per direction
#define G4   1600     // 4*HH
#define FF   512
#define NLAB 9

// ---------------- workspace layout (bytes) ----------------
static const size_t OFF_X    = 0;          // x [4096][300] f32 (4,915,200)  dead after input GEMM
static const size_t OFF_XW   = 5242880;    // XW [2][4096][1600] f32 (52,428,800) dead after LSTM
static const size_t OFF_WHHT = 57671680;   // WhhT [2][400][1600] f32 (5,120,000) dead after LSTM
static const size_t OFF_ENC  = 62914560;   // enc [4096][800] f32 (13,107,200) dead after proj GEMMs
static const size_t OFF_U    = 0;          // U [4096][9][516] f32 (76,087,296) overlays x/XW/WhhT/enc
static const size_t OFF_X1   = 76087296;   // x1 [4096][516] (513 used) (8,454,144)
static const size_t OFF_Y1T  = 84541440;   // y1T [32][513][128] (8,404,992)
static const size_t OFF_KEYS = 92946432;   // keys u64 [32][16384] (4,194,304)
static const size_t OFF_WBP  = 97140736;   // Wb padded [9][513][516] (9,529,488)

// ---------------- embedding gather ----------------
__global__ __launch_bounds__(256) void k_gather(const int* __restrict__ wi,
                                                const float* __restrict__ emb,
                                                float* __restrict__ x) {
  int m = blockIdx.x;                 // 0..4095 = b*128 + l
  int idx = wi[m];
  const float* src = emb + (size_t)idx * EMBD;
  float* dst = x + (size_t)m * EMBD;
  for (int e = threadIdx.x; e < EMBD; e += 256) dst[e] = src[e];
}

// ---------------- Whh transpose: WhhT[d][k][g] = Whh_d[g][k] ----------------
__global__ __launch_bounds__(256) void k_whht(const float* __restrict__ wf,
                                              const float* __restrict__ wb,
                                              float* __restrict__ whhT) {
  int tid = blockIdx.x * 256 + threadIdx.x;
  if (tid >= 2 * HH * G4) return;
  int d = tid / (HH * G4);
  int r = tid - d * (HH * G4);
  int k = r / G4;
  int g = r - k * G4;
  const float* w = d ? wb : wf;
  whhT[tid] = w[(size_t)g * HH + k];
}

// ---------------- W_biaffine pad to stride 516 ----------------
__global__ __launch_bounds__(256) void k_wbpad(const float* __restrict__ wbi,
                                               float* __restrict__ wbp) {
  int tid = blockIdx.x * 256 + threadIdx.x;
  const int PER = 513 * 516;
  if (tid >= 9 * PER) return;
  int o = tid / PER;
  int r = tid - o * PER;
  int i = r / 516;
  int j = r - i * 516;
  wbp[tid] = (j < 513) ? wbi[(size_t)o * 513 * 513 + (size_t)i * 513 + j] : 0.f;
}

// ---------------- ones columns ----------------
__global__ __launch_bounds__(256) void k_ones(float* __restrict__ x1, float* __restrict__ y1T) {
  int tid = blockIdx.x * 256 + threadIdx.x;
  if (tid < 4096) {
    x1[(size_t)tid * 516 + 512] = 1.f;
  } else if (tid < 8192) {
    int r = tid - 4096;
    int bb = r >> 7, y = r & 127;
    y1T[((size_t)bb * 513 + 512) * 128 + y] = 1.f;
  }
}

// ---------------- tiled GEMM, f64 accumulate, C = A * W^T (+b1+b2); mode1 = y1T transposed store ----------------
__global__ __launch_bounds__(256) void k_gemm_nt(const float* __restrict__ A, int lda,
                                                 const float* __restrict__ W, int ldw,
                                                 const float* __restrict__ bias1,
                                                 const float* __restrict__ bias2,
                                                 float* __restrict__ C, int ldc,
                                                 int M, int N, int K, int mode) {
  __shared__ __align__(16) double As[16][68];
  __shared__ __align__(16) double Bs[16][68];
  int t = threadIdx.x;
  int m0 = blockIdx.x * 64, n0 = blockIdx.y * 64;
  int tm = t & 15, tn = t >> 4;
  int ar = t >> 2, akq = t & 3;
  double acc[4][4];
#pragma unroll
  for (int r = 0; r < 4; ++r)
#pragma unroll
    for (int c = 0; c < 4; ++c) acc[r][c] = 0.0;

  for (int k0 = 0; k0 < K; k0 += 16) {
    // stage A tile (transposed into LDS)
    {
      const float* ap = A + (size_t)(m0 + ar) * lda + k0 + 4 * akq;
      float v0, v1, v2, v3;
      if (k0 + 4 * akq + 4 <= K) {
        float4 f = *(const float4*)ap; v0 = f.x; v1 = f.y; v2 = f.z; v3 = f.w;
      } else {
        v0 = (k0 + 4 * akq + 0 < K) ? ap[0] : 0.f;
        v1 = (k0 + 4 * akq + 1 < K) ? ap[1] : 0.f;
        v2 = (k0 + 4 * akq + 2 < K) ? ap[2] : 0.f;
        v3 = (k0 + 4 * akq + 3 < K) ? ap[3] : 0.f;
      }
      As[4 * akq + 0][ar] = (double)v0; As[4 * akq + 1][ar] = (double)v1;
      As[4 * akq + 2][ar] = (double)v2; As[4 * akq + 3][ar] = (double)v3;
    }
    // stage W tile (rows are output features)
    {
      int nr = n0 + ar;
      float v0 = 0.f, v1 = 0.f, v2 = 0.f, v3 = 0.f;
      if (nr < N) {
        const float* wp = W + (size_t)nr * ldw + k0 + 4 * akq;
        if (k0 + 4 * akq + 4 <= K) {
          float4 f = *(const float4*)wp; v0 = f.x; v1 = f.y; v2 = f.z; v3 = f.w;
        } else {
          if (k0 + 4 * akq + 0 < K) v0 = wp[0];
          if (k0 + 4 * akq + 1 < K) v1 = wp[1];
          if (k0 + 4 * akq + 2 < K) v2 = wp[2];
          if (k0 + 4 * akq + 3 < K) v3 = wp[3];
        }
      }
      Bs[4 * akq + 0][ar] = (double)v0; Bs[4 * akq + 1][ar] = (double)v1;
      Bs[4 * akq + 2][ar] = (double)v2; Bs[4 * akq + 3][ar] = (double)v3;
    }
    __syncthreads();
#pragma unroll
    for (int kk = 0; kk < 16; ++kk) {
      double2 a01 = *(const double2*)&As[kk][4 * tm];
      double2 a23 = *(const double2*)&As[kk][4 * tm + 2];
      double2 b01 = *(const double2*)&Bs[kk][4 * tn];
      double2 b23 = *(const double2*)&Bs[kk][4 * tn + 2];
      double av[4] = {a01.x, a01.y, a23.x, a23.y};
      double bv[4] = {b01.x, b01.y, b23.x, b23.y};
#pragma unroll
      for (int r = 0; r < 4; ++r)
#pragma unroll
        for (int c = 0; c < 4; ++c) acc[r][c] = fma(av[r], bv[c], acc[r][c]);
    }
    __syncthreads();
  }
  double bn[4];
#pragma unroll
  for (int c = 0; c < 4; ++c) {
    int n = n0 + 4 * tn + c;
    double bv = 0.0;
    if (n < N) {
      if (bias1) bv += (double)bias1[n];
      if (bias2) bv += (double)bias2[n];
    }
    bn[c] = bv;
  }
  if (mode == 0) {
#pragma unroll
    for (int r = 0; r < 4; ++r) {
      int m = m0 + 4 * tm + r;
      float* cp = C + (size_t)m * ldc + n0 + 4 * tn;
      if (n0 + 4 * tn + 4 <= N) {
        float4 s = make_float4((float)(acc[r][0] + bn[0]), (float)(acc[r][1] + bn[1]),
                               (float)(acc[r][2] + bn[2]), (float)(acc[r][3] + bn[3]));
        *(float4*)cp = s;
      } else {
#pragma unroll
        for (int c = 0; c < 4; ++c)
          if (n0 + 4 * tn + c < N) cp[c] = (float)(acc[r][c] + bn[c]);
      }
    }
  } else {
    // transposed store into y1T[(b*513+n)*128 + y], m = b*128 + y
#pragma unroll
    for (int r = 0; r < 4; ++r) {
      int m = m0 + 4 * tm + r;
      int bb = m >> 7, y = m & 127;
#pragma unroll
      for (int c = 0; c < 4; ++c) {
        int n = n0 + 4 * tn + c;
        if (n < N) C[((size_t)bb * 513 + n) * 128 + y] = (float)(acc[r][c] + bn[c]);
      }
    }
  }
}

// ---------------- tiled GEMM f64-acc, C(+o*516 col) = A * B (B row-major), batched over o ----------------
__global__ __launch_bounds__(256) void k_gemm_nn(const float* __restrict__ A, int lda,
                                                 const float* __restrict__ Bm, int ldb,
                                                 size_t strideB,
                                                 float* __restrict__ C, int ldc,
                                                 int M, int N, int K) {
  __shared__ __align__(16) double As[16][68];
  __shared__ __align__(16) double Bs[16][68];
  int t = threadIdx.x;
  int o = blockIdx.z;
  const float* B = Bm + (size_t)o * strideB;
  float* Cb = C + (size_t)o * 516;
  int m0 = blockIdx.x * 64, n0 = blockIdx.y * 64;
  int tm = t & 15, tn = t >> 4;
  int ar = t >> 2, akq = t & 3;
  double acc[4][4];
#pragma unroll
  for (int r = 0; r < 4; ++r)
#pragma unroll
    for (int c = 0; c < 4; ++c) acc[r][c] = 0.0;

  for (int k0 = 0; k0 < K; k0 += 16) {
    {
      const float* ap = A + (size_t)(m0 + ar) * lda + k0 + 4 * akq;
      float v0, v1, v2, v3;
      if (k0 + 4 * akq + 4 <= K) {
        float4 f = *(const float4*)ap; v0 = f.x; v1 = f.y; v2 = f.z; v3 = f.w;
      } else {
        v0 = (k0 + 4 * akq + 0 < K) ? ap[0] : 0.f;
        v1 = (k0 + 4 * akq + 1 < K) ? ap[1] : 0.f;
        v2 = (k0 + 4 * akq + 2 < K) ? ap[2] : 0.f;
        v3 = (k0 + 4 * akq + 3 < K) ? ap[3] : 0.f;
      }
      As[4 * akq + 0][ar] = (double)v0; As[4 * akq + 1][ar] = (double)v1;
      As[4 * akq + 2][ar] = (double)v2; As[4 * akq + 3][ar] = (double)v3;
    }
    {
      int kr = k0 + (t >> 4);
      int nc = n0 + 4 * (t & 15);
      float v0 = 0.f, v1 = 0.f, v2 = 0.f, v3 = 0.f;
      if (kr < K) {
        const float* bp = B + (size_t)kr * ldb + nc;
        if (nc + 4 <= N) {
          float4 f = *(const float4*)bp; v0 = f.x; v1 = f.y; v2 = f.z; v3 = f.w;
        } else {
          if (nc + 0 < N) v0 = bp[0];
          if (nc + 1 < N) v1 = bp[1];
          if (nc + 2 < N) v2 = bp[2];
          if (nc + 3 < N) v3 = bp[3];
        }
      }
      int kk = t >> 4, nq = 4 * (t & 15);
      Bs[kk][nq + 0] = (double)v0; Bs[kk][nq + 1] = (double)v1;
      Bs[kk][nq + 2] = (double)v2; Bs[kk][nq + 3] = (double)v3;
    }
    __syncthreads();
#pragma unroll
    for (int kk = 0; kk < 16; ++kk) {
      double2 a01 = *(const double2*)&As[kk][4 * tm];
      double2 a23 = *(const double2*)&As[kk][4 * tm + 2];
      double2 b01 = *(const double2*)&Bs[kk][4 * tn];
      double2 b23 = *(const double2*)&Bs[kk][4 * tn + 2];
      double av[4] = {a01.x, a01.y, a23.x, a23.y};
      double bv[4] = {b01.x, b01.y, b23.x, b23.y};
#pragma unroll
      for (int r = 0; r < 4; ++r)
#pragma unroll
        for (int c = 0; c < 4; ++c) acc[r][c] = fma(av[r], bv[c], acc[r][c]);
    }
    __syncthreads();
  }
#pragma unroll
  for (int r = 0; r < 4; ++r) {
    int m = m0 + 4 * tm + r;
    float* cp = Cb + (size_t)m * ldc + n0 + 4 * tn;
    if (n0 + 4 * tn + 4 <= N) {
      *(float4*)cp = make_float4((float)acc[r][0], (float)acc[r][1],
                                 (float)acc[r][2], (float)acc[r][3]);
    } else {
#pragma unroll
      for (int c = 0; c < 4; ++c)
        if (n0 + 4 * tn + c < N) cp[c] = (float)acc[r][c];
    }
  }
}

// ---------------- masked BiLSTM recurrence (f64 state): one block per (dir, batch) ----------------
__global__ __launch_bounds__(448) void k_lstm(const float* __restrict__ xw,
                                              const float* __restrict__ whhT,
                                              const int* __restrict__ word_idxs,
                                              float* __restrict__ enc) {
  int bid = blockIdx.x;
  int d = bid >> 5, b = bid & 31;
  const float* xwb = xw + ((size_t)(d * NB + b)) * SEQL * G4;
  const float* wT = whhT + (size_t)d * HH * G4;
  __shared__ __align__(16) double h[HH];
  __shared__ __align__(16) double c[HH];
  __shared__ __align__(16) double gates[G4];
  int t = threadIdx.x;
  if (t < HH) { h[t] = 0.0; c[t] = 0.0; }
  __syncthreads();
  for (int s = 0; s < SEQL; ++s) {
    int l = d ? (SEQL - 1 - s) : s;
    bool m = word_idxs[b * SEQL + l] > 0;
    if (t < 400) {
      // gates 4t..4t+3
      float4 xa = *(const float4*)(xwb + (size_t)l * G4 + 4 * t);
      double ax = (double)xa.x, ay = (double)xa.y, az = (double)xa.z, aw = (double)xa.w;
      const float* wp = wT + 4 * t;
      for (int k4 = 0; k4 < 100; ++k4) {
        double2 h01 = *(const double2*)&h[4 * k4];
        double2 h23 = *(const double2*)&h[4 * k4 + 2];
        float4 w0 = *(const float4*)(wp + (size_t)(4 * k4 + 0) * G4);
        float4 w1 = *(const float4*)(wp + (size_t)(4 * k4 + 1) * G4);
        float4 w2 = *(const float4*)(wp + (size_t)(4 * k4 + 2) * G4);
        float4 w3 = *(const float4*)(wp + (size_t)(4 * k4 + 3) * G4);
        ax = fma((double)w3.x, h23.y, fma((double)w2.x, h23.x, fma((double)w1.x, h01.y, fma((double)w0.x, h01.x, ax))));
        ay = fma((double)w3.y, h23.y, fma((double)w2.y, h23.x, fma((double)w1.y, h01.y, fma((double)w0.y, h01.x, ay))));
        az = fma((double)w3.z, h23.y, fma((double)w2.z, h23.x, fma((double)w1.z, h01.y, fma((double)w0.z, h01.x, az))));
        aw = fma((double)w3.w, h23.y, fma((double)w2.w, h23.x, fma((double)w1.w, h01.y, fma((double)w0.w, h01.x, aw))));
      }
      gates[4 * t + 0] = ax; gates[4 * t + 1] = ay;
      gates[4 * t + 2] = az; gates[4 * t + 3] = aw;
    }
    __syncthreads();
    if (t < 400) {
      double gi = gates[t], gf = gates[400 + t], gg = gates[800 + t], go = gates[1200 + t];
      double si = 1.0 / (1.0 + exp(-gi));
      double sf = 1.0 / (1.0 + exp(-gf));
      double so = 1.0 / (1.0 + exp(-go));
      double cn = sf * c[t] + si * tanh(gg);
      double hn = so * tanh(cn);
      double hold = h[t], cold = c[t];
      h[t] = m ? hn : hold;
      c[t] = m ? cn : cold;
      enc[((size_t)b * SEQL + l) * 800 + d * HH + t] = m ? (float)hn : 0.f;
    }
    __syncthreads();
  }
}

// ---------------- stage 2: score + argmax per (b,x), emits sort keys ----------------
__global__ __launch_bounds__(128) void k_stage2(const float* __restrict__ U,
                                                const float* __restrict__ y1T,
                                                const int* __restrict__ labels,
                                                unsigned long long* __restrict__ keys) {
  __shared__ double Ur[4644];
  int bx = blockIdx.x;          // b*128 + x
  int b = bx >> 7, x = bx & 127;
  const float* Urow = U + (size_t)bx * 4644;
  for (int i = threadIdx.x; i < 4644; i += 128) Ur[i] = (double)Urow[i];
  __syncthreads();
  int y = threadIdx.x;
  double acc[9];
#pragma unroll
  for (int o = 0; o < 9; ++o) acc[o] = 0.0;
  const float* yb = y1T + (size_t)b * 513 * 128 + y;
  for (int j = 0; j < 513; ++j) {
    double yv = (double)yb[(size_t)j * 128];
#pragma unroll
    for (int o = 0; o < 9; ++o) acc[o] = fma(Ur[o * 516 + j], yv, acc[o]);
  }
  double best = acc[0];
  int bi = 0;
#pragma unroll
  for (int o = 1; o < 9; ++o) {
    if (acc[o] > best) { best = acc[o]; bi = o; }
  }
  int fi = x * 128 + y;                      // per-sentence flat index
  int lab = labels[(size_t)bx * 128 + y];
  bool valid = (bi != 1) && (lab > 0);
  unsigned long long key;
  if (valid) {
    unsigned long long u = (unsigned long long)__double_as_longlong(best);
    unsigned long long mm = (u >> 63) ? ~u : (u | 0x8000000000000000ull); // ascending map
    unsigned long long dm = ~mm;                                          // descending
    key = (dm & ~0x3FFFFull) | ((unsigned long long)(unsigned)fi << 4) |
          (unsigned long long)(unsigned)bi;
  } else {
    key = ~0ull;
  }
  keys[(size_t)b * 16384 + fi] = key;
}

// ---------------- decode helpers ----------------
__device__ __forceinline__ void rangemask(int i, int j,
                                          unsigned long long& r0, unsigned long long& r1) {
  if (i > j) { r0 = 0ull; r1 = 0ull; return; }
  unsigned long long u0, u1;
  if (j >= 64) { u0 = ~0ull; u1 = (j >= 127) ? ~0ull : ((1ull << (j - 63)) - 1ull); }
  else         { u0 = (j == 63) ? ~0ull : ((1ull << (j + 1)) - 1ull); u1 = 0ull; }
  unsigned long long f0, f1;
  if (i >= 64) { f0 = 0ull; f1 = (~0ull) << (i - 64); }
  else         { f0 = (~0ull) << i; f1 = ~0ull; }
  r0 = u0 & f0; r1 = u1 & f1;
}

// ---------------- decode: sort + greedy NMS scan, one block per sentence ----------------
__global__ __launch_bounds__(1024) void k_decode(unsigned long long* __restrict__ keysg,
                                                 int* __restrict__ outp) {
  extern __shared__ unsigned long long lds[];     // 8192 keys = 64 KB
  int b = blockIdx.x;
  int t = threadIdx.x;
  unsigned long long* kg = keysg + (size_t)b * 16384;
  int* ob = outp + (size_t)b * 16384;

  // init output to NON_ENTITY=1
  for (int i = t; i < 16384; i += 1024) ob[i] = 1;
  __syncthreads();

  // bitonic sort 16384 = LDS half-sorts + one global cross pass + LDS merges
  for (int hhalf = 0; hhalf < 2; ++hhalf) {
    for (int i = t; i < 8192; i += 1024) lds[i] = kg[hhalf * 8192 + i];
    __syncthreads();
    bool desc = (hhalf == 1);
    for (int k = 2; k <= 8192; k <<= 1) {
      for (int j = k >> 1; j > 0; j >>= 1) {
        for (int p = 0; p < 8; ++p) {
          int i = p * 1024 + t;
          int ix = i ^ j;
          if (ix > i) {
            unsigned long long ka = lds[i], kb = lds[ix];
            bool up = (((i & k) == 0) != desc);
            if (up ? (ka > kb) : (ka < kb)) { lds[i] = kb; lds[ix] = ka; }
          }
        }
        __syncthreads();
      }
    }
    for (int i = t; i < 8192; i += 1024) kg[hhalf * 8192 + i] = lds[i];
    __syncthreads();
  }
  // global cross pass (k=16384, j=8192), ascending
  for (int i = t; i < 8192; i += 1024) {
    unsigned long long ka = kg[i], kb = kg[i + 8192];
    if (ka > kb) { kg[i] = kb; kg[i + 8192] = ka; }
  }
  __syncthreads();
  for (int hhalf = 0; hhalf < 2; ++hhalf) {
    for (int i = t; i < 8192; i += 1024) lds[i] = kg[hhalf * 8192 + i];
    __syncthreads();
    for (int j = 4096; j > 0; j >>= 1) {
      for (int p = 0; p < 8; ++p) {
        int i = p * 1024 + t;
        int ix = i ^ j;
        if (ix > i) {
          unsigned long long ka = lds[i], kb = lds[ix];
          if (ka > kb) { lds[i] = kb; lds[ix] = ka; }
        }
      }
      __syncthreads();
    }
    for (int i = t; i < 8192; i += 1024) kg[hhalf * 8192 + i] = lds[i];
    __syncthreads();
  }

  // greedy scan: wave 0 only, 64 candidates per batch, order-faithful
  if (t < 64) {
    const int lane = t;
    unsigned long long s0 = 0, s1 = 0, in0 = 0, in1 = 0;   // start / inside masks, replicated
    for (int base = 0; base < 16384; base += 64) {
      unsigned long long key = kg[base + lane];
      bool valid = (key != ~0ull);
      if (__ballot(valid) == 0ull) break;   // sorted: all-invalid suffix
      int fi = (int)((key >> 4) & 0x3FFFull);
      int ci = fi >> 7, cj = fi & 127, ca = (int)(key & 15ull);
      bool alive = valid;
      while (true) {
        bool conflict = false;
        {
          unsigned long long r0, r1;
          rangemask(ci, cj, r0, r1);
          if (((r0 & s0) | (r1 & s1)) != 0ull) conflict = true;
          unsigned long long ib = (ci < 64) ? (in0 >> ci) : (in1 >> (ci - 64));
          if (ib & 1ull) conflict = true;
        }
        unsigned long long elig = __ballot(alive && !conflict);
        if (elig == 0ull) break;
        int w = __ffsll((long long)elig) - 1;
        int wi = __shfl(ci, w), wj = __shfl(cj, w);
        if (lane == w) ob[fi] = ca;
        unsigned long long r0, r1;
        rangemask(wi, wj, r0, r1);
        in0 |= r0; in1 |= r1;
        if (wi < 64) s0 |= (1ull << wi); else s1 |= (1ull << (wi - 64));
        alive = alive && (lane > w);
      }
    }
  }
}

extern "C" void kernel_launch(void* const* d_in, const int* in_sizes, int n_in,
                              void* d_out, int out_size, void* d_ws, size_t ws_size,
                              hipStream_t stream) {
  const int*   word_idxs = (const int*)d_in[0];
  const int*   labels    = (const int*)d_in[1];
  const float* word_emb  = (const float*)d_in[2];
  const float* Wih_f = (const float*)d_in[3];
  const float* Whh_f = (const float*)d_in[4];
  const float* bih_f = (const float*)d_in[5];
  const float* bhh_f = (const float*)d_in[6];
  const float* Wih_b = (const float*)d_in[7];
  const float* Whh_b = (const float*)d_in[8];
  const float* bih_b = (const float*)d_in[9];
  const float* bhh_b = (const float*)d_in[10];
  const float* W_start = (const float*)d_in[11];
  const float* b_start = (const float*)d_in[12];
  const float* W_end   = (const float*)d_in[13];
  const float* b_end   = (const float*)d_in[14];
  const float* W_bi    = (const float*)d_in[15];

  char* ws = (char*)d_ws;
  float* x    = (float*)(ws + OFF_X);
  float* XW   = (float*)(ws + OFF_XW);
  float* WhhT = (float*)(ws + OFF_WHHT);
  float* enc  = (float*)(ws + OFF_ENC);
  float* U    = (float*)(ws + OFF_U);
  float* x1   = (float*)(ws + OFF_X1);
  float* y1T  = (float*)(ws + OFF_Y1T);
  float* Wbp  = (float*)(ws + OFF_WBP);
  unsigned long long* keys = (unsigned long long*)(ws + OFF_KEYS);
  int* outp = (int*)d_out;

  // 1. embedding gather
  k_gather<<<4096, 256, 0, stream>>>(word_idxs, word_emb, x);
  // 2. transpose Whh for coalesced recurrence reads
  k_whht<<<(2 * HH * G4 + 255) / 256, 256, 0, stream>>>(Whh_f, Whh_b, WhhT);
  // 3. input-gate GEMMs (bias folded in)
  dim3 g2(64, 25);
  k_gemm_nt<<<g2, 256, 0, stream>>>(x, EMBD, Wih_f, EMBD, bih_f, bhh_f,
                                    XW, G4, 4096, G4, EMBD, 0);
  k_gemm_nt<<<g2, 256, 0, stream>>>(x, EMBD, Wih_b, EMBD, bih_b, bhh_b,
                                    XW + (size_t)4096 * G4, G4, 4096, G4, EMBD, 0);
  // 4. recurrence
  k_lstm<<<64, 448, 0, stream>>>(XW, WhhT, word_idxs, enc);
  // 5. projections: x1 (hs, normal) and y1T (he, transposed)
  dim3 g4(64, 8);
  k_gemm_nt<<<g4, 256, 0, stream>>>(enc, 800, W_start, 800, b_start, nullptr,
                                    x1, 516, 4096, FF, 800, 0);
  k_gemm_nt<<<g4, 256, 0, stream>>>(enc, 800, W_end, 800, b_end, nullptr,
                                    y1T, 0, 4096, FF, 800, 1);
  k_ones<<<32, 256, 0, stream>>>(x1, y1T);
  // 6. biaffine stage 1: U[b,x][o][j] = sum_i x1[b,x,i] W[o,i,j]
  k_wbpad<<<(9 * 513 * 516 + 255) / 256, 256, 0, stream>>>(W_bi, Wbp);
  dim3 g5(64, 9, 9);
  k_gemm_nn<<<g5, 256, 0, stream>>>(x1, 516, Wbp, 516, (size_t)513 * 516,
                                    U, 4644, 4096, 513, 513);
  // 7. stage 2 + argmax + key build
  k_stage2<<<4096, 128, 0, stream>>>(U, y1T, labels, keys);
  // 8. sort + greedy NMS decode
  k_decode<<<32, 1024, 65536, stream>>>(keys, outp);
}